// Round 2
// baseline (281.444 us; speedup 1.0000x reference)
//
#include <hip/hip_runtime.h>
#include <math.h>

#define G 32
#define IMG_W 512
#define IMG_H 512
#define NPIX (IMG_W * IMG_H)
#define NIMG 128
#define BAND_ROWS 128   // 4 bands per image

__device__ __forceinline__ int quantize(float v) {
    int q = (int)(v * 31.0f);   // matches (img*31).astype(int32): RN multiply, trunc convert
    return q > 31 ? 31 : q;
}

// 512 blocks = 128 images x 4 row-bands. Each block builds a private 4x1024
// LDS histogram for its 128-row band and atomically merges into the per-image
// global histogram ghist[img*4096].
__global__ __launch_bounds__(1024) void glcm_hist_kernel(
    const float* __restrict__ x, const float* __restrict__ y,
    unsigned int* __restrict__ ghist)
{
    __shared__ unsigned int hist[4 * G * G];   // 16 KB

    const int blk = blockIdx.x;
    const int img = blk >> 2;
    const int band = blk & 3;
    const float* base = (img < 64) ? (x + (size_t)img * NPIX)
                                   : (y + (size_t)(img - 64) * NPIX);
    const int t = threadIdx.x;

    #pragma unroll
    for (int k = 0; k < 4; ++k) hist[t + k * 1024] = 0u;
    __syncthreads();

    unsigned int* h0 = hist;
    unsigned int* h1 = hist + 1024;
    unsigned int* h2 = hist + 2048;
    unsigned int* h3 = hist + 3072;

    // thread -> (row within band, 64-col chunk). 128 rows x 8 chunks = 1024.
    const int row = band * BAND_ROWS + (t >> 3);
    const int c0 = (t & 7) << 6;
    const bool rowv = (row < IMG_H - 1);
    const float* rp = base + (size_t)row * IMG_W;
    const float* rq = rp + IMG_W;

    // sliding-lag pair emission (lags pa=q[r][cc-1], pb=q[r+1][cc-1])
    int pa = 0, pb = 0;
    bool lagv = (c0 != 0);
    if (lagv) {
        pa = quantize(rp[c0 - 1]);
        if (rowv) pb = quantize(rq[c0 - 1]);
    }
    for (int cc = c0; cc < c0 + 64; cc += 4) {
        const float4 fa = *reinterpret_cast<const float4*>(rp + cc);
        const int a0 = quantize(fa.x), a1 = quantize(fa.y),
                  a2 = quantize(fa.z), a3 = quantize(fa.w);
        // angle 0: (0,1)
        if (lagv) atomicAdd(&h0[pa * G + a0], 1u);
        atomicAdd(&h0[a0 * G + a1], 1u);
        atomicAdd(&h0[a1 * G + a2], 1u);
        atomicAdd(&h0[a2 * G + a3], 1u);
        if (rowv) {
            const float4 fb = *reinterpret_cast<const float4*>(rq + cc);
            const int b0 = quantize(fb.x), b1 = quantize(fb.y),
                      b2 = quantize(fb.z), b3 = quantize(fb.w);
            if (lagv) {
                atomicAdd(&h1[pa * G + b0], 1u);   // (r,cc-1)->(r+1,cc)
                atomicAdd(&h3[a0 * G + pb], 1u);   // (r,cc)->(r+1,cc-1)
            }
            // angle 1: (1,1)
            atomicAdd(&h1[a0 * G + b1], 1u);
            atomicAdd(&h1[a1 * G + b2], 1u);
            atomicAdd(&h1[a2 * G + b3], 1u);
            // angle 2: (1,0)
            atomicAdd(&h2[a0 * G + b0], 1u);
            atomicAdd(&h2[a1 * G + b1], 1u);
            atomicAdd(&h2[a2 * G + b2], 1u);
            atomicAdd(&h2[a3 * G + b3], 1u);
            // angle 3: (1,-1)
            atomicAdd(&h3[a1 * G + b0], 1u);
            atomicAdd(&h3[a2 * G + b1], 1u);
            atomicAdd(&h3[a3 * G + b2], 1u);
            pb = b3;
        }
        pa = a3;
        lagv = true;
    }
    __syncthreads();

    unsigned int* gh = ghist + (size_t)img * 4096;
    #pragma unroll
    for (int k = 0; k < 4; ++k) {
        const unsigned int v = hist[t + k * 1024];
        if (v) atomicAdd(&gh[t + k * 1024], v);
    }
}

// One block per image: reduce the 3 features per angle from the merged
// global histogram; write 12 floats per image.
__global__ __launch_bounds__(1024) void glcm_feat_kernel(
    const unsigned int* __restrict__ ghist, float* __restrict__ feats)
{
    __shared__ float red[4][16][3];
    const int img = blockIdx.x;
    const int t = threadIdx.x;
    const unsigned int* gh = ghist + (size_t)img * 4096;

    const int i = t >> 5, j = t & 31;
    const int d2 = (i - j) * (i - j);
    const float inv = 1.0f / (1.0f + (float)d2);
    const int lane = t & 63, wave = t >> 6;
    #pragma unroll
    for (int a = 0; a < 4; ++a) {
        const float h  = (float)gh[a * 1024 + i * G + j];
        const float ht = (float)gh[a * 1024 + j * G + i];
        float cs = h * (float)d2;
        float hs = h * inv;
        float es = (h + ht) * (h + ht);
        #pragma unroll
        for (int off = 32; off; off >>= 1) {
            cs += __shfl_down(cs, off);
            hs += __shfl_down(hs, off);
            es += __shfl_down(es, off);
        }
        if (lane == 0) { red[a][wave][0] = cs; red[a][wave][1] = hs; red[a][wave][2] = es; }
    }
    __syncthreads();
    if (t < 4) {
        float cs = 0.f, hs = 0.f, es = 0.f;
        for (int w = 0; w < 16; ++w) {
            cs += red[t][w][0]; hs += red[t][w][1]; es += red[t][w][2];
        }
        // pair counts per angle: (0,1):512*511, (1,1):511*511, (1,0):511*512, (1,-1):511*511
        const float Na = (t == 0 || t == 2) ? 261632.0f : 261121.0f;
        float* o = feats + img * 12 + t * 3;
        o[0] = cs / Na;                    // contrast
        o[1] = sqrtf(es) / (2.0f * Na);    // energy
        o[2] = hs / Na;                    // homogeneity
    }
}

__global__ void loss_kernel(const float* __restrict__ feats, float* __restrict__ out)
{
    const int t = threadIdx.x;  // 256 threads
    float s = 0.0f;
    for (int k = t; k < 768; k += 256)
        s += fabsf(feats[k] - feats[768 + k]);
    #pragma unroll
    for (int off = 32; off; off >>= 1) s += __shfl_down(s, off);
    __shared__ float red[4];
    if ((t & 63) == 0) red[t >> 6] = s;
    __syncthreads();
    if (t == 0) out[0] = (red[0] + red[1] + red[2] + red[3]) * (1.0f / 768.0f);
}

extern "C" void kernel_launch(void* const* d_in, const int* in_sizes, int n_in,
                              void* d_out, int out_size, void* d_ws, size_t ws_size,
                              hipStream_t stream) {
    const float* x = (const float*)d_in[0];
    const float* y = (const float*)d_in[1];
    unsigned int* ghist = (unsigned int*)d_ws;                 // 128*4096*4 = 2 MB
    float* feats = (float*)((char*)d_ws + NIMG * 4096 * 4);    // 6 KB
    float* out = (float*)d_out;

    hipMemsetAsync(ghist, 0, (size_t)NIMG * 4096 * 4, stream);
    hipLaunchKernelGGL(glcm_hist_kernel, dim3(NIMG * 4), dim3(1024), 0, stream,
                       x, y, ghist);
    hipLaunchKernelGGL(glcm_feat_kernel, dim3(NIMG), dim3(1024), 0, stream,
                       ghist, feats);
    hipLaunchKernelGGL(loss_kernel, dim3(1), dim3(256), 0, stream, feats, out);
}

// Round 3
// 53.082 us; speedup vs baseline: 5.3021x; 5.3021x over previous
//
#include <hip/hip_runtime.h>
#include <math.h>

#define G 32
#define IMG_W 512
#define IMG_H 512
#define NPIX (IMG_W * IMG_H)
#define NIMG 128
#define BAND_ROWS 128   // 4 bands per image, 512 blocks total

__device__ __forceinline__ int quantize(float v) {
    int q = (int)(v * 31.0f);   // matches (img*31).astype(int32): RN multiply, trunc convert
    return q > 31 ? 31 : q;
}

// 512 blocks = 128 images x 4 row-bands, 1024 threads (16 waves).
// Wave w owns rows [band*128 + w*8, +8); lane l owns cols [8l, 8l+8).
// Rows are loaded once (coalesced, contiguous 2KB per wave-load pair) and the
// quantized row is carried in registers across the row loop. Cross-lane pairs
// via shuffles. Histograms in LDS, merged to per-image global hist.
__global__ __launch_bounds__(1024) void glcm_hist_kernel(
    const float* __restrict__ x, const float* __restrict__ y,
    unsigned int* __restrict__ ghist)
{
    __shared__ unsigned int hist[4 * G * G];   // 16 KB

    const int blk = blockIdx.x;
    const int img = blk >> 2;
    const int band = blk & 3;
    const float* base = (img < 64) ? (x + (size_t)img * NPIX)
                                   : (y + (size_t)(img - 64) * NPIX);
    const int t = threadIdx.x;

    #pragma unroll
    for (int k = 0; k < 4; ++k) hist[t + k * 1024] = 0u;
    __syncthreads();

    unsigned int* h0 = hist;            // angle (0,1)
    unsigned int* h1 = hist + 1024;     // angle (1,1)
    unsigned int* h2 = hist + 2048;     // angle (1,0)
    unsigned int* h3 = hist + 3072;     // angle (1,-1)

    const int wave = t >> 6, lane = t & 63;
    const int r0 = band * BAND_ROWS + wave * 8;
    const float* rowp = base + (size_t)r0 * IMG_W + lane * 8;

    int qc[8];
    {
        const float4 f0 = *reinterpret_cast<const float4*>(rowp);
        const float4 f1 = *reinterpret_cast<const float4*>(rowp + 4);
        qc[0] = quantize(f0.x); qc[1] = quantize(f0.y);
        qc[2] = quantize(f0.z); qc[3] = quantize(f0.w);
        qc[4] = quantize(f1.x); qc[5] = quantize(f1.y);
        qc[6] = quantize(f1.z); qc[7] = quantize(f1.w);
    }

    for (int r = r0; r < r0 + 8; ++r) {
        const bool havenext = (r + 1 < IMG_H);
        // horizontal pairs on current row (angle 0)
        const int nx0 = __shfl_down(qc[0], 1);
        #pragma unroll
        for (int k = 0; k < 7; ++k)
            atomicAdd(&h0[qc[k] * G + qc[k + 1]], 1u);
        if (lane < 63) atomicAdd(&h0[qc[7] * G + nx0], 1u);

        if (havenext) {
            rowp += IMG_W;
            int qn[8];
            const float4 f0 = *reinterpret_cast<const float4*>(rowp);
            const float4 f1 = *reinterpret_cast<const float4*>(rowp + 4);
            qn[0] = quantize(f0.x); qn[1] = quantize(f0.y);
            qn[2] = quantize(f0.z); qn[3] = quantize(f0.w);
            qn[4] = quantize(f1.x); qn[5] = quantize(f1.y);
            qn[6] = quantize(f1.z); qn[7] = quantize(f1.w);

            const int nqn0 = __shfl_down(qn[0], 1);   // next lane's qn[0]
            const int pqn7 = __shfl_up(qn[7], 1);     // prev lane's qn[7]
            // vertical (angle 2)
            #pragma unroll
            for (int k = 0; k < 8; ++k)
                atomicAdd(&h2[qc[k] * G + qn[k]], 1u);
            // diag (1,1) (angle 1)
            #pragma unroll
            for (int k = 0; k < 7; ++k)
                atomicAdd(&h1[qc[k] * G + qn[k + 1]], 1u);
            if (lane < 63) atomicAdd(&h1[qc[7] * G + nqn0], 1u);
            // diag (1,-1) (angle 3)
            #pragma unroll
            for (int k = 1; k < 8; ++k)
                atomicAdd(&h3[qc[k] * G + qn[k - 1]], 1u);
            if (lane > 0) atomicAdd(&h3[qc[0] * G + pqn7], 1u);

            #pragma unroll
            for (int k = 0; k < 8; ++k) qc[k] = qn[k];
        }
    }
    __syncthreads();

    unsigned int* gh = ghist + (size_t)img * 4096;
    #pragma unroll
    for (int k = 0; k < 4; ++k) {
        const unsigned int v = hist[t + k * 1024];
        if (v) atomicAdd(&gh[t + k * 1024], v);
    }
}

// One block per image: reduce the 3 features per angle from the merged
// global histogram; write 12 floats per image.
__global__ __launch_bounds__(1024) void glcm_feat_kernel(
    const unsigned int* __restrict__ ghist, float* __restrict__ feats)
{
    __shared__ float red[4][16][3];
    const int img = blockIdx.x;
    const int t = threadIdx.x;
    const unsigned int* gh = ghist + (size_t)img * 4096;

    const int i = t >> 5, j = t & 31;
    const int d2 = (i - j) * (i - j);
    const float inv = 1.0f / (1.0f + (float)d2);
    const int lane = t & 63, wave = t >> 6;
    #pragma unroll
    for (int a = 0; a < 4; ++a) {
        const float h  = (float)gh[a * 1024 + i * G + j];
        const float ht = (float)gh[a * 1024 + j * G + i];
        float cs = h * (float)d2;
        float hs = h * inv;
        float es = (h + ht) * (h + ht);
        #pragma unroll
        for (int off = 32; off; off >>= 1) {
            cs += __shfl_down(cs, off);
            hs += __shfl_down(hs, off);
            es += __shfl_down(es, off);
        }
        if (lane == 0) { red[a][wave][0] = cs; red[a][wave][1] = hs; red[a][wave][2] = es; }
    }
    __syncthreads();
    if (t < 4) {
        float cs = 0.f, hs = 0.f, es = 0.f;
        for (int w = 0; w < 16; ++w) {
            cs += red[t][w][0]; hs += red[t][w][1]; es += red[t][w][2];
        }
        // pair counts: (0,1):512*511, (1,1):511*511, (1,0):511*512, (1,-1):511*511
        const float Na = (t == 0 || t == 2) ? 261632.0f : 261121.0f;
        float* o = feats + img * 12 + t * 3;
        o[0] = cs / Na;                    // contrast
        o[1] = sqrtf(es) / (2.0f * Na);    // energy
        o[2] = hs / Na;                    // homogeneity
    }
}

__global__ void loss_kernel(const float* __restrict__ feats, float* __restrict__ out)
{
    const int t = threadIdx.x;  // 256 threads
    float s = 0.0f;
    for (int k = t; k < 768; k += 256)
        s += fabsf(feats[k] - feats[768 + k]);
    #pragma unroll
    for (int off = 32; off; off >>= 1) s += __shfl_down(s, off);
    __shared__ float red[4];
    if ((t & 63) == 0) red[t >> 6] = s;
    __syncthreads();
    if (t == 0) out[0] = (red[0] + red[1] + red[2] + red[3]) * (1.0f / 768.0f);
}

extern "C" void kernel_launch(void* const* d_in, const int* in_sizes, int n_in,
                              void* d_out, int out_size, void* d_ws, size_t ws_size,
                              hipStream_t stream) {
    const float* x = (const float*)d_in[0];
    const float* y = (const float*)d_in[1];
    unsigned int* ghist = (unsigned int*)d_ws;                 // 128*4096*4 = 2 MB
    float* feats = (float*)((char*)d_ws + NIMG * 4096 * 4);    // 6 KB
    float* out = (float*)d_out;

    hipMemsetAsync(ghist, 0, (size_t)NIMG * 4096 * 4, stream);
    hipLaunchKernelGGL(glcm_hist_kernel, dim3(NIMG * 4), dim3(1024), 0, stream,
                       x, y, ghist);
    hipLaunchKernelGGL(glcm_feat_kernel, dim3(NIMG), dim3(1024), 0, stream,
                       ghist, feats);
    hipLaunchKernelGGL(loss_kernel, dim3(1), dim3(256), 0, stream, feats, out);
}